// Round 4
// baseline (670.017 us; speedup 1.0000x reference)
//
#include <hip/hip_runtime.h>
#include <stdint.h>

#define S_ 1024
#define D_ 64
#define B_ 64

typedef short short8 __attribute__((ext_vector_type(8)));
typedef unsigned short ushort8 __attribute__((ext_vector_type(8)));
typedef float f32x4 __attribute__((ext_vector_type(4)));

// lgkm-only barrier: does NOT drain vmcnt, so global prefetches survive.
// No intra-kernel cross-thread global communication -> safe.
#define LBAR() do { asm volatile("s_waitcnt lgkmcnt(0)" ::: "memory"); \
                    __builtin_amdgcn_s_barrier(); } while (0)

__device__ __forceinline__ unsigned short f2bf(float x) {
    uint32_t u = __builtin_bit_cast(uint32_t, x);
    return (unsigned short)((u + 0x7FFFu + ((u >> 16) & 1u)) >> 16);
}
__device__ __forceinline__ float bf2f(unsigned short b) {
    return __builtin_bit_cast(float, ((uint32_t)b) << 16);
}
__device__ __forceinline__ uint32_t pack2(float a, float b) {
    return (uint32_t)f2bf(a) | ((uint32_t)f2bf(b) << 16);
}
// XOR-swizzled index into the 32x1024 bf16 score buffer (16B-chunk swizzle by row&15)
__device__ __forceinline__ int scidx(int row, int k) {
    return (((row << 10) + (k & ~7)) ^ ((row & 15) << 3)) + (k & 7);
}

// ---------------- K1: qk[b,q,k] = Q[b,q,:].K[b,k,:]  (writes f32 into attn region)
__global__ __launch_bounds__(256) void k1_qk(const float* __restrict__ Q,
                                             const float* __restrict__ Kk,
                                             float* __restrict__ qk) {
    __shared__ __align__(16) unsigned short Qs[128][72];
    __shared__ __align__(16) unsigned short Ks[128][72];
    const int bx = blockIdx.x;
    const int b  = bx >> 6;
    const int q0 = ((bx >> 3) & 7) << 7;
    const int k0 = (bx & 7) << 7;
    const int t  = threadIdx.x;
#pragma unroll
    for (int i = 0; i < 8; ++i) {
        int f = (i << 8) + t;
        int row = f >> 4, c = (f & 15) << 2;
        float4 v = *reinterpret_cast<const float4*>(&Q[((size_t)(b * S_ + q0 + row) << 6) + c]);
        *reinterpret_cast<uint2*>(&Qs[row][c]) = make_uint2(pack2(v.x, v.y), pack2(v.z, v.w));
        float4 u = *reinterpret_cast<const float4*>(&Kk[((size_t)(b * S_ + k0 + row) << 6) + c]);
        *reinterpret_cast<uint2*>(&Ks[row][c]) = make_uint2(pack2(u.x, u.y), pack2(u.z, u.w));
    }
    __syncthreads();
    const int l = t & 63, w = t >> 6, lr = l & 15, lg = l >> 4;
    short8 a[2][2];
#pragma unroll
    for (int mi = 0; mi < 2; ++mi)
#pragma unroll
        for (int h = 0; h < 2; ++h)
            a[mi][h] = *reinterpret_cast<const short8*>(&Qs[((w * 2 + mi) << 4) + lr][h * 32 + lg * 8]);
    f32x4 acc[2][8] = {};
#pragma unroll
    for (int n = 0; n < 8; ++n) {
        short8 b0 = *reinterpret_cast<const short8*>(&Ks[(n << 4) + lr][lg * 8]);
        short8 b1 = *reinterpret_cast<const short8*>(&Ks[(n << 4) + lr][32 + lg * 8]);
#pragma unroll
        for (int mi = 0; mi < 2; ++mi) {
            acc[mi][n] = __builtin_amdgcn_mfma_f32_16x16x32_bf16(a[mi][0], b0, acc[mi][n], 0, 0, 0);
            acc[mi][n] = __builtin_amdgcn_mfma_f32_16x16x32_bf16(a[mi][1], b1, acc[mi][n], 0, 0, 0);
        }
    }
#pragma unroll
    for (int mi = 0; mi < 2; ++mi)
#pragma unroll
        for (int n = 0; n < 8; ++n)
#pragma unroll
            for (int r = 0; r < 4; ++r) {
                int qq = q0 + ((w * 2 + mi) << 4) + (lg << 2) + r;
                int kc = k0 + (n << 4) + lr;
                qk[((size_t)(b * S_ + qq) << 10) + kc] = acc[mi][n][r];
            }
}

// in-register 4x4 transpose (lanes l, l^16, l^32, l^48) then b64 LDS store: T[d][k]
__device__ __forceinline__ void tpose_store(unsigned short (*Tls)[72], float4 p,
                                            int i, int t) {
    const int l = t & 63, w = t >> 6, lr = l & 15, lg = l >> 4;
    float v0 = p.x, v1 = p.y, v2 = p.z, v3 = p.w;
    float y0 = __shfl_xor(v0, 16), y1 = __shfl_xor(v1, 16),
          y2 = __shfl_xor(v2, 16), y3 = __shfl_xor(v3, 16);
    bool o = (lg & 1);
    float n0 = o ? y1 : v0, n1 = o ? v1 : y0, n2 = o ? y3 : v2, n3 = o ? v3 : y2;
    float z0 = __shfl_xor(n0, 32), z1 = __shfl_xor(n1, 32),
          z2 = __shfl_xor(n2, 32), z3 = __shfl_xor(n3, 32);
    bool h = (lg & 2);
    float T0 = h ? z2 : n0, T1 = h ? z3 : n1, T2 = h ? n2 : z0, T3 = h ? n3 : z1;
    int d = (lr << 2) + lg, kb = (i << 4) + (w << 2);
    *reinterpret_cast<uint2*>(&Tls[d][kb]) = make_uint2(pack2(T0, T1), pack2(T2, T3));
}

// ---------------- K2: per (q, 32-batch group): rel scores + softmax + attn + rel_qkv
__global__ __launch_bounds__(256) void k2_mid(const float* __restrict__ Q,
                                              const float* __restrict__ AK,
                                              const float* __restrict__ AV,
                                              float* __restrict__ attn,
                                              float* __restrict__ outp) {
    __shared__ __align__(16) unsigned short Sc[32 * 1024];
    __shared__ __align__(16) unsigned short Qs[32][72];
    __shared__ __align__(16) unsigned short Ak[64][72];
    __shared__ float invs[32];
    const float SCL = 0.18033688011112042f;  // log2(e)/8
    // XCD-pair swizzle: the 2 blocks sharing q land on the same XCD, 8 apart.
    const int j = blockIdx.x;
    const int xcd = j & 7, slot = j >> 3;
    const int q  = xcd * 128 + (slot >> 1);
    const int b0 = (slot & 1) << 5;
    const int t  = threadIdx.x;
    const int l = t & 63, w = t >> 6, lr = l & 15, lg = l >> 4;

#pragma unroll
    for (int i = 0; i < 2; ++i) {   // Qs (pre-scaled by SCL), 32 rows x 64
        int f = (i << 8) + t;
        int row = f >> 4, c = (f & 15) << 2;
        float4 v = *reinterpret_cast<const float4*>(&Q[((size_t)((b0 + row) * S_ + q) << 6) + c]);
        *reinterpret_cast<uint2*>(&Qs[row][c]) =
            make_uint2(pack2(v.x * SCL, v.y * SCL), pack2(v.z * SCL, v.w * SCL));
    }
    const float* akbase = &AK[(size_t)q << 16];
    float4 pf[2][4];
#pragma unroll
    for (int d2 = 0; d2 < 2; ++d2)
#pragma unroll
        for (int i = 0; i < 4; ++i) {
            int f = (i << 8) + t;
            pf[d2][i] = *reinterpret_cast<const float4*>(
                &akbase[(size_t)(d2 << 12) + ((size_t)(f >> 4) << 6) + ((f & 15) << 2)]);
        }
    // init Sc = qk * SCL (coalesced: per row, 256 threads cover 1024 cols)
#pragma unroll 8
    for (int i = 0; i < 32; ++i) {
        int col = t << 2;
        float4 v = *reinterpret_cast<const float4*>(&attn[((size_t)((b0 + i) * S_ + q) << 10) + col]);
        *reinterpret_cast<uint2*>(&Sc[scidx(i, col)]) =
            make_uint2(pack2(v.x * SCL, v.y * SCL), pack2(v.z * SCL, v.w * SCL));
    }
    LBAR();
    // Q fragments (lane = batch within half, per d-half)
    short8 qa[2][2];
#pragma unroll
    for (int bh = 0; bh < 2; ++bh)
#pragma unroll
        for (int h = 0; h < 2; ++h)
            qa[bh][h] = *reinterpret_cast<const short8*>(&Qs[(bh << 4) + lr][(h << 5) + (lg << 3)]);

    // ---- phase A: Sc[batch][k] += (AKtile . (Q*SCL)^T), C read/written as b64
    for (int tt = 0; tt < 16; ++tt) {
        LBAR();
#pragma unroll
        for (int i = 0; i < 4; ++i) {
            int f = (i << 8) + t;
            int row = f >> 4, c = (f & 15) << 2;
            *reinterpret_cast<uint2*>(&Ak[row][c]) =
                make_uint2(pack2(pf[tt & 1][i].x, pf[tt & 1][i].y),
                           pack2(pf[tt & 1][i].z, pf[tt & 1][i].w));
        }
        LBAR();
        if (tt < 14) {
            const float* nb = akbase + (((size_t)(tt + 2)) << 12);
#pragma unroll
            for (int i = 0; i < 4; ++i) {
                int f = (i << 8) + t;
                pf[tt & 1][i] = *reinterpret_cast<const float4*>(
                    &nb[((size_t)(f >> 4) << 6) + ((f & 15) << 2)]);
            }
        }
        short8 ak0 = *reinterpret_cast<const short8*>(&Ak[(w << 4) + lr][lg << 3]);
        short8 ak1 = *reinterpret_cast<const short8*>(&Ak[(w << 4) + lr][32 + (lg << 3)]);
        int kbase = (tt << 6) + (w << 4) + (lg << 2);
#pragma unroll
        for (int bh = 0; bh < 2; ++bh) {
            int idx = scidx((bh << 4) + lr, kbase);
            uint2 cu = *reinterpret_cast<const uint2*>(&Sc[idx]);
            f32x4 c;
            c[0] = bf2f((unsigned short)(cu.x & 0xffff));
            c[1] = bf2f((unsigned short)(cu.x >> 16));
            c[2] = bf2f((unsigned short)(cu.y & 0xffff));
            c[3] = bf2f((unsigned short)(cu.y >> 16));
            c = __builtin_amdgcn_mfma_f32_16x16x32_bf16(ak0, qa[bh][0], c, 0, 0, 0);
            c = __builtin_amdgcn_mfma_f32_16x16x32_bf16(ak1, qa[bh][1], c, 0, 0, 0);
            *reinterpret_cast<uint2*>(&Sc[idx]) =
                make_uint2(pack2(c[0], c[1]), pack2(c[2], c[3]));
        }
    }
    LBAR();

    // prefetch AV tiles 0,1 (in flight during the whole softmax)
    const float* avbase = &AV[(size_t)q << 16];
    float4 pv[2][4];
#pragma unroll
    for (int d2 = 0; d2 < 2; ++d2)
#pragma unroll
        for (int i = 0; i < 4; ++i) {
            int f = (i << 8) + t;
            pv[d2][i] = *reinterpret_cast<const float4*>(
                &avbase[(size_t)(d2 << 12) + ((size_t)(f >> 4) << 6) + ((f & 15) << 2)]);
        }

    // ---- softmax: 32 rows, 8 threads/row, interleaved chunks (LDS-only)
    {
        int row = t >> 3, ch = t & 7;
        float m = -1e30f;
#pragma unroll
        for (int i = 0; i < 16; ++i) {
            int k = (((i << 3) + ch) << 3);
            ushort8 v = *reinterpret_cast<const ushort8*>(&Sc[scidx(row, k)]);
#pragma unroll
            for (int jj = 0; jj < 8; ++jj) m = fmaxf(m, bf2f(v[jj]));
        }
#pragma unroll
        for (int d = 1; d < 8; d <<= 1) m = fmaxf(m, __shfl_xor(m, d));
        float s = 0.f;
#pragma unroll 4
        for (int i = 0; i < 16; ++i) {
            int idx = scidx(row, (((i << 3) + ch) << 3));
            ushort8 v = *reinterpret_cast<const ushort8*>(&Sc[idx]);
            ushort8 e;
#pragma unroll
            for (int jj = 0; jj < 8; ++jj) {
                float ev = exp2f(bf2f(v[jj]) - m);
                s += ev;
                e[jj] = f2bf(ev);
            }
            *reinterpret_cast<ushort8*>(&Sc[idx]) = e;
        }
#pragma unroll
        for (int d = 1; d < 8; d <<= 1) s += __shfl_xor(s, d);
        float inv = 1.0f / s;
        if (ch == 0) invs[row] = inv;
    }
    LBAR();

    // write attn (coalesced: per row, 256 threads cover 1024 cols)
#pragma unroll 8
    for (int i = 0; i < 32; ++i) {
        int col = t << 2;
        uint2 u = *reinterpret_cast<const uint2*>(&Sc[scidx(i, col)]);
        float inv = invs[i];
        float4 o = make_float4(bf2f((unsigned short)(u.x & 0xffff)) * inv,
                               bf2f((unsigned short)(u.x >> 16)) * inv,
                               bf2f((unsigned short)(u.y & 0xffff)) * inv,
                               bf2f((unsigned short)(u.y >> 16)) * inv);
        *reinterpret_cast<float4*>(&attn[((size_t)((b0 + i) * S_ + q) << 10) + col]) = o;
    }

    // ---- phase B: out_rel = (e . a_value[q]) * inv   M=32 N=64 K=1024
    f32x4 oacc[2] = {};
    for (int tt = 0; tt < 16; ++tt) {
        LBAR();
#pragma unroll
        for (int i = 0; i < 4; ++i) tpose_store(Ak, pv[tt & 1][i], i, t);
        LBAR();
        if (tt < 14) {
            const float* nb = avbase + (((size_t)(tt + 2)) << 12);
#pragma unroll
            for (int i = 0; i < 4; ++i) {
                int f = (i << 8) + t;
                pv[tt & 1][i] = *reinterpret_cast<const float4*>(
                    &nb[((size_t)(f >> 4) << 6) + ((f & 15) << 2)]);
            }
        }
        short8 bb0 = *reinterpret_cast<const short8*>(&Ak[(w << 4) + lr][lg << 3]);
        short8 bb1 = *reinterpret_cast<const short8*>(&Ak[(w << 4) + lr][32 + (lg << 3)]);
#pragma unroll
        for (int mi = 0; mi < 2; ++mi) {
            short8 ea0 = *reinterpret_cast<const short8*>(&Sc[scidx((mi << 4) + lr, (tt << 6) + (lg << 3))]);
            short8 ea1 = *reinterpret_cast<const short8*>(&Sc[scidx((mi << 4) + lr, (tt << 6) + 32 + (lg << 3))]);
            oacc[mi] = __builtin_amdgcn_mfma_f32_16x16x32_bf16(ea0, bb0, oacc[mi], 0, 0, 0);
            oacc[mi] = __builtin_amdgcn_mfma_f32_16x16x32_bf16(ea1, bb1, oacc[mi], 0, 0, 0);
        }
    }
#pragma unroll
    for (int mi = 0; mi < 2; ++mi)
#pragma unroll
        for (int r = 0; r < 4; ++r) {
            int brow = (mi << 4) + (lg << 2) + r;
            outp[((size_t)((b0 + brow) * S_ + q) << 6) + (w << 4) + lr] = oacc[mi][r] * invs[brow];
        }
}

// ---------------- K3: out += attn[b] . V[b]
__global__ __launch_bounds__(256) void k3_pv(const float* __restrict__ V,
                                             const float* __restrict__ attn,
                                             float* __restrict__ outp) {
    __shared__ __align__(16) unsigned short At[64][72];
    __shared__ __align__(16) unsigned short Vt[64][72];
    const int b  = blockIdx.x >> 4;
    const int q0 = (blockIdx.x & 15) << 6;
    const int t  = threadIdx.x;
    const int l = t & 63, w = t >> 6, lr = l & 15, lg = l >> 4;
    float4 pa[4], pv[4];
#pragma unroll
    for (int i = 0; i < 4; ++i) {
        int f = (i << 8) + t;
        int row = f >> 4, c = (f & 15) << 2;
        pa[i] = *reinterpret_cast<const float4*>(&attn[((size_t)(b * S_ + q0 + row) << 10) + c]);
        pv[i] = *reinterpret_cast<const float4*>(&V[((size_t)(b * S_ + row) << 6) + c]);
    }
    f32x4 acc[4] = {};
    for (int tt = 0; tt < 16; ++tt) {
        LBAR();
#pragma unroll
        for (int i = 0; i < 4; ++i) {
            int f = (i << 8) + t;
            int row = f >> 4, c = (f & 15) << 2;
            *reinterpret_cast<uint2*>(&At[row][c]) =
                make_uint2(pack2(pa[i].x, pa[i].y), pack2(pa[i].z, pa[i].w));
            tpose_store(Vt, pv[i], i, t);
        }
        LBAR();
        if (tt < 15) {
#pragma unroll
            for (int i = 0; i < 4; ++i) {
                int f = (i << 8) + t;
                int row = f >> 4, c = (f & 15) << 2;
                pa[i] = *reinterpret_cast<const float4*>(
                    &attn[((size_t)(b * S_ + q0 + row) << 10) + ((tt + 1) << 6) + c]);
                pv[i] = *reinterpret_cast<const float4*>(
                    &V[((size_t)(b * S_ + ((tt + 1) << 6) + row) << 6) + c]);
            }
        }
        short8 a0 = *reinterpret_cast<const short8*>(&At[(w << 4) + lr][lg * 8]);
        short8 a1 = *reinterpret_cast<const short8*>(&At[(w << 4) + lr][32 + lg * 8]);
#pragma unroll
        for (int n = 0; n < 4; ++n) {
            short8 b0 = *reinterpret_cast<const short8*>(&Vt[(n << 4) + lr][lg * 8]);
            short8 b1 = *reinterpret_cast<const short8*>(&Vt[(n << 4) + lr][32 + lg * 8]);
            acc[n] = __builtin_amdgcn_mfma_f32_16x16x32_bf16(a0, b0, acc[n], 0, 0, 0);
            acc[n] = __builtin_amdgcn_mfma_f32_16x16x32_bf16(a1, b1, acc[n], 0, 0, 0);
        }
    }
#pragma unroll
    for (int n = 0; n < 4; ++n)
#pragma unroll
        for (int r = 0; r < 4; ++r) {
            size_t idx = ((size_t)(b * S_ + q0 + (w << 4) + (lg << 2) + r) << 6) + (n << 4) + lr;
            outp[idx] += acc[n][r];
        }
}

extern "C" void kernel_launch(void* const* d_in, const int* in_sizes, int n_in,
                              void* d_out, int out_size, void* d_ws, size_t ws_size,
                              hipStream_t stream) {
    (void)in_sizes; (void)n_in; (void)out_size; (void)d_ws; (void)ws_size;
    const float* Q  = (const float*)d_in[0];
    const float* K  = (const float*)d_in[1];
    const float* V  = (const float*)d_in[2];
    const float* AK = (const float*)d_in[3];
    const float* AV = (const float*)d_in[4];
    float* outp = (float*)d_out;
    float* attn = outp + (size_t)B_ * S_ * D_;

    k1_qk <<<dim3(64 * 8 * 8), dim3(256), 0, stream>>>(Q, K, attn);
    k2_mid<<<dim3(2048),       dim3(256), 0, stream>>>(Q, AK, AV, attn, outp);
    k3_pv <<<dim3(64 * 16),    dim3(256), 0, stream>>>(V, attn, outp);
}

// Round 5
// 464.779 us; speedup vs baseline: 1.4416x; 1.4416x over previous
//
#include <hip/hip_runtime.h>
#include <stdint.h>

#define S_ 1024
#define D_ 64
#define B_ 64

typedef short short8 __attribute__((ext_vector_type(8)));
typedef unsigned short ushort8 __attribute__((ext_vector_type(8)));
typedef float f32x4 __attribute__((ext_vector_type(4)));

__device__ __forceinline__ unsigned short f2bf(float x) {
    uint32_t u = __builtin_bit_cast(uint32_t, x);
    return (unsigned short)((u + 0x7FFFu + ((u >> 16) & 1u)) >> 16);
}
__device__ __forceinline__ float bf2f(unsigned short b) {
    return __builtin_bit_cast(float, ((uint32_t)b) << 16);
}
__device__ __forceinline__ uint32_t pack2(float a, float b) {
    return (uint32_t)f2bf(a) | ((uint32_t)f2bf(b) << 16);
}
__device__ __forceinline__ short8 mkfrag(float4 a, float4 b) {
    union { short8 s; uint32_t u[4]; } r;
    r.u[0] = pack2(a.x, a.y); r.u[1] = pack2(a.z, a.w);
    r.u[2] = pack2(b.x, b.y); r.u[3] = pack2(b.z, b.w);
    return r.s;
}
// XOR-swizzled index into the 32x1024 bf16 score buffer (16B-chunk swizzle by row&15)
__device__ __forceinline__ int scidx(int row, int k) {
    return (((row << 10) + (k & ~7)) ^ ((row & 15) << 3)) + (k & 7);
}

// ---------------- K1: qk[b,q,k] = Q[b,q,:].K[b,k,:]  (writes f32 into attn region)
__global__ __launch_bounds__(256) void k1_qk(const float* __restrict__ Q,
                                             const float* __restrict__ Kk,
                                             float* __restrict__ qk) {
    __shared__ __align__(16) unsigned short Qs[128][72];
    __shared__ __align__(16) unsigned short Ks[128][72];
    const int bx = blockIdx.x;
    const int b  = bx >> 6;
    const int q0 = ((bx >> 3) & 7) << 7;
    const int k0 = (bx & 7) << 7;
    const int t  = threadIdx.x;
#pragma unroll
    for (int i = 0; i < 8; ++i) {
        int f = (i << 8) + t;
        int row = f >> 4, c = (f & 15) << 2;
        float4 v = *reinterpret_cast<const float4*>(&Q[((size_t)(b * S_ + q0 + row) << 6) + c]);
        *reinterpret_cast<uint2*>(&Qs[row][c]) = make_uint2(pack2(v.x, v.y), pack2(v.z, v.w));
        float4 u = *reinterpret_cast<const float4*>(&Kk[((size_t)(b * S_ + k0 + row) << 6) + c]);
        *reinterpret_cast<uint2*>(&Ks[row][c]) = make_uint2(pack2(u.x, u.y), pack2(u.z, u.w));
    }
    __syncthreads();
    const int l = t & 63, w = t >> 6, lr = l & 15, lg = l >> 4;
    short8 a[2][2];
#pragma unroll
    for (int mi = 0; mi < 2; ++mi)
#pragma unroll
        for (int h = 0; h < 2; ++h)
            a[mi][h] = *reinterpret_cast<const short8*>(&Qs[((w * 2 + mi) << 4) + lr][h * 32 + lg * 8]);
    f32x4 acc[2][8] = {};
#pragma unroll
    for (int n = 0; n < 8; ++n) {
        short8 b0 = *reinterpret_cast<const short8*>(&Ks[(n << 4) + lr][lg * 8]);
        short8 b1 = *reinterpret_cast<const short8*>(&Ks[(n << 4) + lr][32 + lg * 8]);
#pragma unroll
        for (int mi = 0; mi < 2; ++mi) {
            acc[mi][n] = __builtin_amdgcn_mfma_f32_16x16x32_bf16(a[mi][0], b0, acc[mi][n], 0, 0, 0);
            acc[mi][n] = __builtin_amdgcn_mfma_f32_16x16x32_bf16(a[mi][1], b1, acc[mi][n], 0, 0, 0);
        }
    }
#pragma unroll
    for (int mi = 0; mi < 2; ++mi)
#pragma unroll
        for (int n = 0; n < 8; ++n)
#pragma unroll
            for (int r = 0; r < 4; ++r) {
                int qq = q0 + ((w * 2 + mi) << 4) + (lg << 2) + r;
                int kc = k0 + (n << 4) + lr;
                qk[((size_t)(b * S_ + qq) << 10) + kc] = acc[mi][n][r];
            }
}

// in-register 4x4 transpose (lanes l, l^16, l^32, l^48) then b64 LDS store: T[d][k]
__device__ __forceinline__ void tpose_store(unsigned short (*Tls)[72], float4 p,
                                            int i, int t) {
    const int l = t & 63, w = t >> 6, lr = l & 15, lg = l >> 4;
    float v0 = p.x, v1 = p.y, v2 = p.z, v3 = p.w;
    float y0 = __shfl_xor(v0, 16), y1 = __shfl_xor(v1, 16),
          y2 = __shfl_xor(v2, 16), y3 = __shfl_xor(v3, 16);
    bool o = (lg & 1);
    float n0 = o ? y1 : v0, n1 = o ? v1 : y0, n2 = o ? y3 : v2, n3 = o ? v3 : y2;
    float z0 = __shfl_xor(n0, 32), z1 = __shfl_xor(n1, 32),
          z2 = __shfl_xor(n2, 32), z3 = __shfl_xor(n3, 32);
    bool h = (lg & 2);
    float T0 = h ? z2 : n0, T1 = h ? z3 : n1, T2 = h ? n2 : z0, T3 = h ? n3 : z1;
    int d = (lr << 2) + lg, kb = (i << 4) + (w << 2);
    *reinterpret_cast<uint2*>(&Tls[d][kb]) = make_uint2(pack2(T0, T1), pack2(T2, T3));
}

// ---------------- K2: per (q, 32-batch group): rel scores + softmax + attn + rel_qkv
__global__ __launch_bounds__(256) void k2_mid(const float* __restrict__ Q,
                                              const float* __restrict__ AK,
                                              const float* __restrict__ AV,
                                              float* __restrict__ attn,
                                              float* __restrict__ outp) {
    __shared__ __align__(16) unsigned short Sc[32 * 1024];
    __shared__ __align__(16) unsigned short Qs[32][72];
    __shared__ __align__(16) unsigned short Ak[64][72];
    __shared__ float invs[32];
    const float SCL = 0.18033688011112042f;  // log2(e)/8
    // XCD-pair swizzle: the 2 blocks sharing q land on the same XCD, 8 apart.
    const int j = blockIdx.x;
    const int xcd = j & 7, slot = j >> 3;
    const int q  = xcd * 128 + (slot >> 1);
    const int b0 = (slot & 1) << 5;
    const int t  = threadIdx.x;
    const int l = t & 63, w = t >> 6, lr = l & 15, lg = l >> 4;

#pragma unroll
    for (int i = 0; i < 2; ++i) {   // Qs (pre-scaled by SCL), 32 rows x 64
        int f = (i << 8) + t;
        int row = f >> 4, c = (f & 15) << 2;
        float4 v = *reinterpret_cast<const float4*>(&Q[((size_t)((b0 + row) * S_ + q) << 6) + c]);
        *reinterpret_cast<uint2*>(&Qs[row][c]) =
            make_uint2(pack2(v.x * SCL, v.y * SCL), pack2(v.z * SCL, v.w * SCL));
    }
    // init Sc = qk * SCL (coalesced: per row, 256 threads cover 1024 cols)
#pragma unroll 8
    for (int i = 0; i < 32; ++i) {
        int col = t << 2;
        float4 v = *reinterpret_cast<const float4*>(&attn[((size_t)((b0 + i) * S_ + q) << 10) + col]);
        *reinterpret_cast<uint2*>(&Sc[scidx(i, col)]) =
            make_uint2(pack2(v.x * SCL, v.y * SCL), pack2(v.z * SCL, v.w * SCL));
    }
    __syncthreads();
    // Q fragments (lane = batch within half, per d-half)
    short8 qa[2][2];
#pragma unroll
    for (int bh = 0; bh < 2; ++bh)
#pragma unroll
        for (int h = 0; h < 2; ++h)
            qa[bh][h] = *reinterpret_cast<const short8*>(&Qs[(bh << 4) + lr][(h << 5) + (lg << 3)]);

    // ---- phase A (barrier-free): Sc[batch][k] += AKtile . (Q*SCL)^T
    // AK fragments loaded DIRECTLY from global: lane reads row kpos=(w<<4)+lr,
    // d = lg*8..+7 (lo half) and 32+lg*8..+7 (hi half). 2-deep register pipeline.
    {
        const float* akrow = &AK[((size_t)q << 16) + (((w << 4) + lr) << 6) + (lg << 3)];
        float4 ta[2], tb[2], tc[2], td[2];
#define LDA(buf, tt) do { const float* p_ = akrow + ((size_t)(tt) << 12);            \
        ta[buf] = *reinterpret_cast<const float4*>(p_);                              \
        tb[buf] = *reinterpret_cast<const float4*>(p_ + 4);                          \
        tc[buf] = *reinterpret_cast<const float4*>(p_ + 32);                         \
        td[buf] = *reinterpret_cast<const float4*>(p_ + 36); } while (0)
        LDA(0, 0); LDA(1, 1);
#pragma unroll 2
        for (int tt = 0; tt < 16; ++tt) {
            const int buf = tt & 1;
            short8 ak0 = mkfrag(ta[buf], tb[buf]);
            short8 ak1 = mkfrag(tc[buf], td[buf]);
            if (tt < 14) LDA(buf, tt + 2);
            int kbase = (tt << 6) + (w << 4) + (lg << 2);
#pragma unroll
            for (int bh = 0; bh < 2; ++bh) {
                int idx = scidx((bh << 4) + lr, kbase);
                uint2 cu = *reinterpret_cast<const uint2*>(&Sc[idx]);
                f32x4 c;
                c[0] = bf2f((unsigned short)(cu.x & 0xffff));
                c[1] = bf2f((unsigned short)(cu.x >> 16));
                c[2] = bf2f((unsigned short)(cu.y & 0xffff));
                c[3] = bf2f((unsigned short)(cu.y >> 16));
                c = __builtin_amdgcn_mfma_f32_16x16x32_bf16(ak0, qa[bh][0], c, 0, 0, 0);
                c = __builtin_amdgcn_mfma_f32_16x16x32_bf16(ak1, qa[bh][1], c, 0, 0, 0);
                *reinterpret_cast<uint2*>(&Sc[idx]) =
                    make_uint2(pack2(c[0], c[1]), pack2(c[2], c[3]));
            }
        }
#undef LDA
    }
    __syncthreads();

    // prefetch AV tile 0 (in flight during the softmax)
    const float* avbase = &AV[(size_t)q << 16];
    float4 pv[4];
#pragma unroll
    for (int i = 0; i < 4; ++i) {
        int f = (i << 8) + t;
        pv[i] = *reinterpret_cast<const float4*>(
            &avbase[((size_t)(f >> 4) << 6) + ((f & 15) << 2)]);
    }

    // ---- softmax: 32 rows, 8 threads/row, interleaved chunks (LDS-only)
    {
        int row = t >> 3, ch = t & 7;
        float m = -1e30f;
#pragma unroll
        for (int i = 0; i < 16; ++i) {
            int k = (((i << 3) + ch) << 3);
            ushort8 v = *reinterpret_cast<const ushort8*>(&Sc[scidx(row, k)]);
#pragma unroll
            for (int jj = 0; jj < 8; ++jj) m = fmaxf(m, bf2f(v[jj]));
        }
#pragma unroll
        for (int d = 1; d < 8; d <<= 1) m = fmaxf(m, __shfl_xor(m, d));
        float s = 0.f;
#pragma unroll 4
        for (int i = 0; i < 16; ++i) {
            int idx = scidx(row, (((i << 3) + ch) << 3));
            ushort8 v = *reinterpret_cast<const ushort8*>(&Sc[idx]);
            ushort8 e;
#pragma unroll
            for (int jj = 0; jj < 8; ++jj) {
                float ev = exp2f(bf2f(v[jj]) - m);
                s += ev;
                e[jj] = f2bf(ev);
            }
            *reinterpret_cast<ushort8*>(&Sc[idx]) = e;
        }
#pragma unroll
        for (int d = 1; d < 8; d <<= 1) s += __shfl_xor(s, d);
        float inv = 1.0f / s;
        if (ch == 0) invs[row] = inv;
    }
    __syncthreads();

    // write attn (coalesced: per row, 256 threads cover 1024 cols)
#pragma unroll 8
    for (int i = 0; i < 32; ++i) {
        int col = t << 2;
        uint2 u = *reinterpret_cast<const uint2*>(&Sc[scidx(i, col)]);
        float inv = invs[i];
        float4 o = make_float4(bf2f((unsigned short)(u.x & 0xffff)) * inv,
                               bf2f((unsigned short)(u.x >> 16)) * inv,
                               bf2f((unsigned short)(u.y & 0xffff)) * inv,
                               bf2f((unsigned short)(u.y >> 16)) * inv);
        *reinterpret_cast<float4*>(&attn[((size_t)((b0 + i) * S_ + q) << 10) + col]) = o;
    }

    // ---- phase B: out_rel = (e . a_value[q]) * inv   M=32 N=64 K=1024
    f32x4 oacc[2] = {};
    for (int tt = 0; tt < 16; ++tt) {
        __syncthreads();
#pragma unroll
        for (int i = 0; i < 4; ++i) tpose_store(Ak, pv[i], i, t);
        __syncthreads();
        if (tt < 15) {
            const float* nb = avbase + (((size_t)(tt + 1)) << 12);
#pragma unroll
            for (int i = 0; i < 4; ++i) {
                int f = (i << 8) + t;
                pv[i] = *reinterpret_cast<const float4*>(
                    &nb[((size_t)(f >> 4) << 6) + ((f & 15) << 2)]);
            }
        }
        short8 bb0 = *reinterpret_cast<const short8*>(&Ak[(w << 4) + lr][lg << 3]);
        short8 bb1 = *reinterpret_cast<const short8*>(&Ak[(w << 4) + lr][32 + (lg << 3)]);
#pragma unroll
        for (int mi = 0; mi < 2; ++mi) {
            short8 ea0 = *reinterpret_cast<const short8*>(&Sc[scidx((mi << 4) + lr, (tt << 6) + (lg << 3))]);
            short8 ea1 = *reinterpret_cast<const short8*>(&Sc[scidx((mi << 4) + lr, (tt << 6) + 32 + (lg << 3))]);
            oacc[mi] = __builtin_amdgcn_mfma_f32_16x16x32_bf16(ea0, bb0, oacc[mi], 0, 0, 0);
            oacc[mi] = __builtin_amdgcn_mfma_f32_16x16x32_bf16(ea1, bb1, oacc[mi], 0, 0, 0);
        }
    }
#pragma unroll
    for (int mi = 0; mi < 2; ++mi)
#pragma unroll
        for (int r = 0; r < 4; ++r) {
            int brow = (mi << 4) + (lg << 2) + r;
            outp[((size_t)((b0 + brow) * S_ + q) << 6) + (w << 4) + lr] = oacc[mi][r] * invs[brow];
        }
}

// ---------------- K3: out += attn[b] . V[b]
__global__ __launch_bounds__(256) void k3_pv(const float* __restrict__ V,
                                             const float* __restrict__ attn,
                                             float* __restrict__ outp) {
    __shared__ __align__(16) unsigned short At[64][72];
    __shared__ __align__(16) unsigned short Vt[64][72];
    const int b  = blockIdx.x >> 4;
    const int q0 = (blockIdx.x & 15) << 6;
    const int t  = threadIdx.x;
    const int l = t & 63, w = t >> 6, lr = l & 15, lg = l >> 4;
    float4 pa[4], pv[4];
#pragma unroll
    for (int i = 0; i < 4; ++i) {
        int f = (i << 8) + t;
        int row = f >> 4, c = (f & 15) << 2;
        pa[i] = *reinterpret_cast<const float4*>(&attn[((size_t)(b * S_ + q0 + row) << 10) + c]);
        pv[i] = *reinterpret_cast<const float4*>(&V[((size_t)(b * S_ + row) << 6) + c]);
    }
    f32x4 acc[4] = {};
    for (int tt = 0; tt < 16; ++tt) {
        __syncthreads();
#pragma unroll
        for (int i = 0; i < 4; ++i) {
            int f = (i << 8) + t;
            int row = f >> 4, c = (f & 15) << 2;
            *reinterpret_cast<uint2*>(&At[row][c]) =
                make_uint2(pack2(pa[i].x, pa[i].y), pack2(pa[i].z, pa[i].w));
            tpose_store(Vt, pv[i], i, t);
        }
        __syncthreads();
        if (tt < 15) {
#pragma unroll
            for (int i = 0; i < 4; ++i) {
                int f = (i << 8) + t;
                int row = f >> 4, c = (f & 15) << 2;
                pa[i] = *reinterpret_cast<const float4*>(
                    &attn[((size_t)(b * S_ + q0 + row) << 10) + ((tt + 1) << 6) + c]);
                pv[i] = *reinterpret_cast<const float4*>(
                    &V[((size_t)(b * S_ + ((tt + 1) << 6) + row) << 6) + c]);
            }
        }
        short8 a0 = *reinterpret_cast<const short8*>(&At[(w << 4) + lr][lg * 8]);
        short8 a1 = *reinterpret_cast<const short8*>(&At[(w << 4) + lr][32 + lg * 8]);
#pragma unroll
        for (int n = 0; n < 4; ++n) {
            short8 b0 = *reinterpret_cast<const short8*>(&Vt[(n << 4) + lr][lg * 8]);
            short8 b1 = *reinterpret_cast<const short8*>(&Vt[(n << 4) + lr][32 + lg * 8]);
            acc[n] = __builtin_amdgcn_mfma_f32_16x16x32_bf16(a0, b0, acc[n], 0, 0, 0);
            acc[n] = __builtin_amdgcn_mfma_f32_16x16x32_bf16(a1, b1, acc[n], 0, 0, 0);
        }
    }
#pragma unroll
    for (int n = 0; n < 4; ++n)
#pragma unroll
        for (int r = 0; r < 4; ++r) {
            size_t idx = ((size_t)(b * S_ + q0 + (w << 4) + (lg << 2) + r) << 6) + (n << 4) + lr;
            outp[idx] += acc[n][r];
        }
}

extern "C" void kernel_launch(void* const* d_in, const int* in_sizes, int n_in,
                              void* d_out, int out_size, void* d_ws, size_t ws_size,
                              hipStream_t stream) {
    (void)in_sizes; (void)n_in; (void)out_size; (void)d_ws; (void)ws_size;
    const float* Q  = (const float*)d_in[0];
    const float* K  = (const float*)d_in[1];
    const float* V  = (const float*)d_in[2];
    const float* AK = (const float*)d_in[3];
    const float* AV = (const float*)d_in[4];
    float* outp = (float*)d_out;
    float* attn = outp + (size_t)B_ * S_ * D_;

    k1_qk <<<dim3(64 * 8 * 8), dim3(256), 0, stream>>>(Q, K, attn);
    k2_mid<<<dim3(2048),       dim3(256), 0, stream>>>(Q, AK, AV, attn, outp);
    k3_pv <<<dim3(64 * 16),    dim3(256), 0, stream>>>(V, attn, outp);
}

// Round 6
// 453.456 us; speedup vs baseline: 1.4776x; 1.0250x over previous
//
#include <hip/hip_runtime.h>
#include <stdint.h>

#define S_ 1024
#define D_ 64
#define B_ 64

typedef short short8 __attribute__((ext_vector_type(8)));
typedef unsigned short ushort8 __attribute__((ext_vector_type(8)));
typedef float f32x4 __attribute__((ext_vector_type(4)));

__device__ __forceinline__ unsigned short f2bf(float x) {
    uint32_t u = __builtin_bit_cast(uint32_t, x);
    return (unsigned short)((u + 0x7FFFu + ((u >> 16) & 1u)) >> 16);
}
__device__ __forceinline__ float bf2f(unsigned short b) {
    return __builtin_bit_cast(float, ((uint32_t)b) << 16);
}
__device__ __forceinline__ uint32_t pack2(float a, float b) {
    return (uint32_t)f2bf(a) | ((uint32_t)f2bf(b) << 16);
}
// XOR-swizzled index into the 32x1024 bf16 score buffer (16B-chunk swizzle by row&15)
__device__ __forceinline__ int scidx(int row, int k) {
    return (((row << 10) + (k & ~7)) ^ ((row & 15) << 3)) + (k & 7);
}

// ---------------- K1: qk[b,q,k] = Q[b,q,:].K[b,k,:]  (writes f32 into attn region)
__global__ __launch_bounds__(256) void k1_qk(const float* __restrict__ Q,
                                             const float* __restrict__ Kk,
                                             float* __restrict__ qk) {
    __shared__ __align__(16) unsigned short Qs[128][72];
    __shared__ __align__(16) unsigned short Ks[128][72];
    const int bx = blockIdx.x;
    const int b  = bx >> 6;
    const int q0 = ((bx >> 3) & 7) << 7;
    const int k0 = (bx & 7) << 7;
    const int t  = threadIdx.x;
#pragma unroll
    for (int i = 0; i < 8; ++i) {
        int f = (i << 8) + t;
        int row = f >> 4, c = (f & 15) << 2;
        float4 v = *reinterpret_cast<const float4*>(&Q[((size_t)(b * S_ + q0 + row) << 6) + c]);
        *reinterpret_cast<uint2*>(&Qs[row][c]) = make_uint2(pack2(v.x, v.y), pack2(v.z, v.w));
        float4 u = *reinterpret_cast<const float4*>(&Kk[((size_t)(b * S_ + k0 + row) << 6) + c]);
        *reinterpret_cast<uint2*>(&Ks[row][c]) = make_uint2(pack2(u.x, u.y), pack2(u.z, u.w));
    }
    __syncthreads();
    const int l = t & 63, w = t >> 6, lr = l & 15, lg = l >> 4;
    short8 a[2][2];
#pragma unroll
    for (int mi = 0; mi < 2; ++mi)
#pragma unroll
        for (int h = 0; h < 2; ++h)
            a[mi][h] = *reinterpret_cast<const short8*>(&Qs[((w * 2 + mi) << 4) + lr][h * 32 + lg * 8]);
    f32x4 acc[2][8] = {};
#pragma unroll
    for (int n = 0; n < 8; ++n) {
        short8 b0 = *reinterpret_cast<const short8*>(&Ks[(n << 4) + lr][lg * 8]);
        short8 b1 = *reinterpret_cast<const short8*>(&Ks[(n << 4) + lr][32 + lg * 8]);
#pragma unroll
        for (int mi = 0; mi < 2; ++mi) {
            acc[mi][n] = __builtin_amdgcn_mfma_f32_16x16x32_bf16(a[mi][0], b0, acc[mi][n], 0, 0, 0);
            acc[mi][n] = __builtin_amdgcn_mfma_f32_16x16x32_bf16(a[mi][1], b1, acc[mi][n], 0, 0, 0);
        }
    }
#pragma unroll
    for (int mi = 0; mi < 2; ++mi)
#pragma unroll
        for (int n = 0; n < 8; ++n)
#pragma unroll
            for (int r = 0; r < 4; ++r) {
                int qq = q0 + ((w * 2 + mi) << 4) + (lg << 2) + r;
                int kc = k0 + (n << 4) + lr;
                qk[((size_t)(b * S_ + qq) << 10) + kc] = acc[mi][n][r];
            }
}

// in-register 4x4 transpose (lanes l, l^16, l^32, l^48) then b64 LDS store: T[d][k]
__device__ __forceinline__ void tpose_store(unsigned short (*Tls)[72], float4 p,
                                            int i, int t) {
    const int l = t & 63, w = t >> 6, lr = l & 15, lg = l >> 4;
    float v0 = p.x, v1 = p.y, v2 = p.z, v3 = p.w;
    float y0 = __shfl_xor(v0, 16), y1 = __shfl_xor(v1, 16),
          y2 = __shfl_xor(v2, 16), y3 = __shfl_xor(v3, 16);
    bool o = (lg & 1);
    float n0 = o ? y1 : v0, n1 = o ? v1 : y0, n2 = o ? y3 : v2, n3 = o ? v3 : y2;
    float z0 = __shfl_xor(n0, 32), z1 = __shfl_xor(n1, 32),
          z2 = __shfl_xor(n2, 32), z3 = __shfl_xor(n3, 32);
    bool h = (lg & 2);
    float T0 = h ? z2 : n0, T1 = h ? z3 : n1, T2 = h ? n2 : z0, T3 = h ? n3 : z1;
    int d = (lr << 2) + lg, kb = (i << 4) + (w << 2);
    *reinterpret_cast<uint2*>(&Tls[d][kb]) = make_uint2(pack2(T0, T1), pack2(T2, T3));
}

// ---------------- K2: per (q, 32-batch group): rel scores + softmax + attn + rel_qkv
__global__ __launch_bounds__(256) void k2_mid(const float* __restrict__ Q,
                                              const float* __restrict__ AK,
                                              const float* __restrict__ AV,
                                              float* __restrict__ attn,
                                              float* __restrict__ outp) {
    __shared__ __align__(16) unsigned short Sc[32 * 1024];
    __shared__ __align__(16) unsigned short Qs[32][72];
    __shared__ __align__(16) unsigned short Ak[64][72];
    __shared__ float invs[32];
    const float SCL = 0.18033688011112042f;  // log2(e)/8
    // XCD-pair swizzle: the 2 blocks sharing q land on the same XCD, 8 apart.
    const int j = blockIdx.x;
    const int xcd = j & 7, slot = j >> 3;
    const int q  = xcd * 128 + (slot >> 1);
    const int b0 = (slot & 1) << 5;
    const int t  = threadIdx.x;
    const int l = t & 63, w = t >> 6, lr = l & 15, lg = l >> 4;

#pragma unroll
    for (int i = 0; i < 2; ++i) {   // Qs (pre-scaled by SCL), 32 rows x 64
        int f = (i << 8) + t;
        int row = f >> 4, c = (f & 15) << 2;
        float4 v = *reinterpret_cast<const float4*>(&Q[((size_t)((b0 + row) * S_ + q) << 6) + c]);
        *reinterpret_cast<uint2*>(&Qs[row][c]) =
            make_uint2(pack2(v.x * SCL, v.y * SCL), pack2(v.z * SCL, v.w * SCL));
    }
    const float* akbase = &AK[(size_t)q << 16];
    float4 pf[4];
#pragma unroll
    for (int i = 0; i < 4; ++i) {   // prefetch AK tile 0
        int f = (i << 8) + t;
        pf[i] = *reinterpret_cast<const float4*>(&akbase[((size_t)(f >> 4) << 6) + ((f & 15) << 2)]);
    }
    __syncthreads();
    // Q fragments (lane = batch within half, per d-half)
    short8 qa[2][2];
#pragma unroll
    for (int bh = 0; bh < 2; ++bh)
#pragma unroll
        for (int h = 0; h < 2; ++h)
            qa[bh][h] = *reinterpret_cast<const short8*>(&Qs[(bh << 4) + lr][(h << 5) + (lg << 3)]);

    // ---- phase A: Sc[batch][k] = AKtile . (Q*SCL)^T  (C=0, pure b64 writes)
    for (int tt = 0; tt < 16; ++tt) {
        __syncthreads();
#pragma unroll
        for (int i = 0; i < 4; ++i) {
            int f = (i << 8) + t;
            int row = f >> 4, c = (f & 15) << 2;
            *reinterpret_cast<uint2*>(&Ak[row][c]) =
                make_uint2(pack2(pf[i].x, pf[i].y), pack2(pf[i].z, pf[i].w));
        }
        __syncthreads();
        if (tt < 15) {
            const float* nb = akbase + (((size_t)(tt + 1)) << 12);
#pragma unroll
            for (int i = 0; i < 4; ++i) {
                int f = (i << 8) + t;
                pf[i] = *reinterpret_cast<const float4*>(&nb[((size_t)(f >> 4) << 6) + ((f & 15) << 2)]);
            }
        }
        short8 ak0 = *reinterpret_cast<const short8*>(&Ak[(w << 4) + lr][lg << 3]);
        short8 ak1 = *reinterpret_cast<const short8*>(&Ak[(w << 4) + lr][32 + (lg << 3)]);
        int kbase = (tt << 6) + (w << 4) + (lg << 2);
#pragma unroll
        for (int bh = 0; bh < 2; ++bh) {
            f32x4 c = {};
            c = __builtin_amdgcn_mfma_f32_16x16x32_bf16(ak0, qa[bh][0], c, 0, 0, 0);
            c = __builtin_amdgcn_mfma_f32_16x16x32_bf16(ak1, qa[bh][1], c, 0, 0, 0);
            *reinterpret_cast<uint2*>(&Sc[scidx((bh << 4) + lr, kbase)]) =
                make_uint2(pack2(c[0], c[1]), pack2(c[2], c[3]));
        }
    }
    __syncthreads();   // Sc (rel logits) complete

    // prefetch AV tile 0 (in flight through combine/sum/attn-write)
    const float* avbase = &AV[(size_t)q << 16];
    float4 pv[4];
#pragma unroll
    for (int i = 0; i < 4; ++i) {
        int f = (i << 8) + t;
        pv[i] = *reinterpret_cast<const float4*>(
            &avbase[((size_t)(f >> 4) << 6) + ((f & 15) << 2)]);
    }

    // ---- combine: P = exp2(qk*SCL + rel)  (no max subtraction; logits ~<=8)
    // coalesced: per row, 256 threads cover 1024 cols (float4 per thread)
#pragma unroll 8
    for (int i = 0; i < 32; ++i) {
        int col = t << 2;
        float4 g = *reinterpret_cast<const float4*>(&attn[((size_t)((b0 + i) * S_ + q) << 10) + col]);
        int idx = scidx(i, col);
        uint2 cu = *reinterpret_cast<const uint2*>(&Sc[idx]);
        float p0 = exp2f(fmaf(g.x, SCL, bf2f((unsigned short)(cu.x & 0xffff))));
        float p1 = exp2f(fmaf(g.y, SCL, bf2f((unsigned short)(cu.x >> 16))));
        float p2 = exp2f(fmaf(g.z, SCL, bf2f((unsigned short)(cu.y & 0xffff))));
        float p3 = exp2f(fmaf(g.w, SCL, bf2f((unsigned short)(cu.y >> 16))));
        *reinterpret_cast<uint2*>(&Sc[idx]) = make_uint2(pack2(p0, p1), pack2(p2, p3));
    }
    __syncthreads();

    // ---- row sums: 32 rows, 8 threads/row, interleaved chunks
    {
        int row = t >> 3, ch = t & 7;
        float s = 0.f;
#pragma unroll 4
        for (int i = 0; i < 16; ++i) {
            ushort8 v = *reinterpret_cast<const ushort8*>(&Sc[scidx(row, (((i << 3) + ch) << 3))]);
#pragma unroll
            for (int jj = 0; jj < 8; ++jj) s += bf2f(v[jj]);
        }
#pragma unroll
        for (int d = 1; d < 8; d <<= 1) s += __shfl_xor(s, d);
        if (ch == 0) invs[row] = 1.0f / s;
    }
    __syncthreads();

    // ---- write attn = P * inv (coalesced)
#pragma unroll 8
    for (int i = 0; i < 32; ++i) {
        int col = t << 2;
        uint2 u = *reinterpret_cast<const uint2*>(&Sc[scidx(i, col)]);
        float inv = invs[i];
        float4 o = make_float4(bf2f((unsigned short)(u.x & 0xffff)) * inv,
                               bf2f((unsigned short)(u.x >> 16)) * inv,
                               bf2f((unsigned short)(u.y & 0xffff)) * inv,
                               bf2f((unsigned short)(u.y >> 16)) * inv);
        *reinterpret_cast<float4*>(&attn[((size_t)((b0 + i) * S_ + q) << 10) + col]) = o;
    }

    // ---- phase B: out_rel = (P . a_value[q]) * inv   M=32 N=64 K=1024
    f32x4 oacc[2] = {};
    for (int tt = 0; tt < 16; ++tt) {
        __syncthreads();
#pragma unroll
        for (int i = 0; i < 4; ++i) tpose_store(Ak, pv[i], i, t);
        __syncthreads();
        if (tt < 15) {
            const float* nb = avbase + (((size_t)(tt + 1)) << 12);
#pragma unroll
            for (int i = 0; i < 4; ++i) {
                int f = (i << 8) + t;
                pv[i] = *reinterpret_cast<const float4*>(
                    &nb[((size_t)(f >> 4) << 6) + ((f & 15) << 2)]);
            }
        }
        short8 bb0 = *reinterpret_cast<const short8*>(&Ak[(w << 4) + lr][lg << 3]);
        short8 bb1 = *reinterpret_cast<const short8*>(&Ak[(w << 4) + lr][32 + (lg << 3)]);
#pragma unroll
        for (int mi = 0; mi < 2; ++mi) {
            short8 ea0 = *reinterpret_cast<const short8*>(&Sc[scidx((mi << 4) + lr, (tt << 6) + (lg << 3))]);
            short8 ea1 = *reinterpret_cast<const short8*>(&Sc[scidx((mi << 4) + lr, (tt << 6) + 32 + (lg << 3))]);
            oacc[mi] = __builtin_amdgcn_mfma_f32_16x16x32_bf16(ea0, bb0, oacc[mi], 0, 0, 0);
            oacc[mi] = __builtin_amdgcn_mfma_f32_16x16x32_bf16(ea1, bb1, oacc[mi], 0, 0, 0);
        }
    }
#pragma unroll
    for (int mi = 0; mi < 2; ++mi)
#pragma unroll
        for (int r = 0; r < 4; ++r) {
            int brow = (mi << 4) + (lg << 2) + r;
            outp[((size_t)((b0 + brow) * S_ + q) << 6) + (w << 4) + lr] = oacc[mi][r] * invs[brow];
        }
}

// ---------------- K3: out += attn[b] . V[b]
__global__ __launch_bounds__(256) void k3_pv(const float* __restrict__ V,
                                             const float* __restrict__ attn,
                                             float* __restrict__ outp) {
    __shared__ __align__(16) unsigned short At[64][72];
    __shared__ __align__(16) unsigned short Vt[64][72];
    const int b  = blockIdx.x >> 4;
    const int q0 = (blockIdx.x & 15) << 6;
    const int t  = threadIdx.x;
    const int l = t & 63, w = t >> 6, lr = l & 15, lg = l >> 4;
    float4 pa[4], pv[4];
#pragma unroll
    for (int i = 0; i < 4; ++i) {
        int f = (i << 8) + t;
        int row = f >> 4, c = (f & 15) << 2;
        pa[i] = *reinterpret_cast<const float4*>(&attn[((size_t)(b * S_ + q0 + row) << 10) + c]);
        pv[i] = *reinterpret_cast<const float4*>(&V[((size_t)(b * S_ + row) << 6) + c]);
    }
    f32x4 acc[4] = {};
    for (int tt = 0; tt < 16; ++tt) {
        __syncthreads();
#pragma unroll
        for (int i = 0; i < 4; ++i) {
            int f = (i << 8) + t;
            int row = f >> 4, c = (f & 15) << 2;
            *reinterpret_cast<uint2*>(&At[row][c]) =
                make_uint2(pack2(pa[i].x, pa[i].y), pack2(pa[i].z, pa[i].w));
            tpose_store(Vt, pv[i], i, t);
        }
        __syncthreads();
        if (tt < 15) {
#pragma unroll
            for (int i = 0; i < 4; ++i) {
                int f = (i << 8) + t;
                int row = f >> 4, c = (f & 15) << 2;
                pa[i] = *reinterpret_cast<const float4*>(
                    &attn[((size_t)(b * S_ + q0 + row) << 10) + ((tt + 1) << 6) + c]);
                pv[i] = *reinterpret_cast<const float4*>(
                    &V[((size_t)(b * S_ + ((tt + 1) << 6) + row) << 6) + c]);
            }
        }
        short8 a0 = *reinterpret_cast<const short8*>(&At[(w << 4) + lr][lg * 8]);
        short8 a1 = *reinterpret_cast<const short8*>(&At[(w << 4) + lr][32 + lg * 8]);
#pragma unroll
        for (int n = 0; n < 4; ++n) {
            short8 b0 = *reinterpret_cast<const short8*>(&Vt[(n << 4) + lr][lg * 8]);
            short8 b1 = *reinterpret_cast<const short8*>(&Vt[(n << 4) + lr][32 + lg * 8]);
            acc[n] = __builtin_amdgcn_mfma_f32_16x16x32_bf16(a0, b0, acc[n], 0, 0, 0);
            acc[n] = __builtin_amdgcn_mfma_f32_16x16x32_bf16(a1, b1, acc[n], 0, 0, 0);
        }
    }
#pragma unroll
    for (int n = 0; n < 4; ++n)
#pragma unroll
        for (int r = 0; r < 4; ++r) {
            size_t idx = ((size_t)(b * S_ + q0 + (w << 4) + (lg << 2) + r) << 6) + (n << 4) + lr;
            outp[idx] += acc[n][r];
        }
}

extern "C" void kernel_launch(void* const* d_in, const int* in_sizes, int n_in,
                              void* d_out, int out_size, void* d_ws, size_t ws_size,
                              hipStream_t stream) {
    (void)in_sizes; (void)n_in; (void)out_size; (void)d_ws; (void)ws_size;
    const float* Q  = (const float*)d_in[0];
    const float* K  = (const float*)d_in[1];
    const float* V  = (const float*)d_in[2];
    const float* AK = (const float*)d_in[3];
    const float* AV = (const float*)d_in[4];
    float* outp = (float*)d_out;
    float* attn = outp + (size_t)B_ * S_ * D_;

    k1_qk <<<dim3(64 * 8 * 8), dim3(256), 0, stream>>>(Q, K, attn);
    k2_mid<<<dim3(2048),       dim3(256), 0, stream>>>(Q, AK, AV, attn, outp);
    k3_pv <<<dim3(64 * 16),    dim3(256), 0, stream>>>(V, attn, outp);
}

// Round 7
// 407.220 us; speedup vs baseline: 1.6453x; 1.1135x over previous
//
#include <hip/hip_runtime.h>
#include <stdint.h>

#define S_ 1024
#define D_ 64
#define B_ 64

typedef short short8 __attribute__((ext_vector_type(8)));
typedef unsigned short ushort8 __attribute__((ext_vector_type(8)));
typedef float f32x4 __attribute__((ext_vector_type(4)));

__device__ __forceinline__ unsigned short f2bf(float x) {
    uint32_t u = __builtin_bit_cast(uint32_t, x);
    return (unsigned short)((u + 0x7FFFu + ((u >> 16) & 1u)) >> 16);
}
__device__ __forceinline__ float bf2f(unsigned short b) {
    return __builtin_bit_cast(float, ((uint32_t)b) << 16);
}
__device__ __forceinline__ uint32_t pack2(float a, float b) {
    return (uint32_t)f2bf(a) | ((uint32_t)f2bf(b) << 16);
}
// XOR-swizzled index into the row x 1024 bf16 score buffer (16B-chunk swizzle by row&15)
__device__ __forceinline__ int scidx(int row, int k) {
    return (((row << 10) + (k & ~7)) ^ ((row & 15) << 3)) + (k & 7);
}

// ---------------- K1: qk[b,q,k] = (Q[b,q,:].K[b,k,:]) * SCL  (f32 into attn region)
__global__ __launch_bounds__(256) void k1_qk(const float* __restrict__ Q,
                                             const float* __restrict__ Kk,
                                             float* __restrict__ qk) {
    __shared__ __align__(16) unsigned short Qs[128][72];
    __shared__ __align__(16) unsigned short Ks[128][72];
    const float SCL = 0.18033688011112042f;  // log2(e)/8
    const int bx = blockIdx.x;
    const int b  = bx >> 6;
    const int q0 = ((bx >> 3) & 7) << 7;
    const int k0 = (bx & 7) << 7;
    const int t  = threadIdx.x;
#pragma unroll
    for (int i = 0; i < 8; ++i) {
        int f = (i << 8) + t;
        int row = f >> 4, c = (f & 15) << 2;
        float4 v = *reinterpret_cast<const float4*>(&Q[((size_t)(b * S_ + q0 + row) << 6) + c]);
        *reinterpret_cast<uint2*>(&Qs[row][c]) = make_uint2(pack2(v.x, v.y), pack2(v.z, v.w));
        float4 u = *reinterpret_cast<const float4*>(&Kk[((size_t)(b * S_ + k0 + row) << 6) + c]);
        *reinterpret_cast<uint2*>(&Ks[row][c]) = make_uint2(pack2(u.x, u.y), pack2(u.z, u.w));
    }
    __syncthreads();
    const int l = t & 63, w = t >> 6, lr = l & 15, lg = l >> 4;
    short8 a[2][2];
#pragma unroll
    for (int mi = 0; mi < 2; ++mi)
#pragma unroll
        for (int h = 0; h < 2; ++h)
            a[mi][h] = *reinterpret_cast<const short8*>(&Qs[((w * 2 + mi) << 4) + lr][h * 32 + lg * 8]);
    f32x4 acc[2][8] = {};
#pragma unroll
    for (int n = 0; n < 8; ++n) {
        short8 b0 = *reinterpret_cast<const short8*>(&Ks[(n << 4) + lr][lg * 8]);
        short8 b1 = *reinterpret_cast<const short8*>(&Ks[(n << 4) + lr][32 + lg * 8]);
#pragma unroll
        for (int mi = 0; mi < 2; ++mi) {
            acc[mi][n] = __builtin_amdgcn_mfma_f32_16x16x32_bf16(a[mi][0], b0, acc[mi][n], 0, 0, 0);
            acc[mi][n] = __builtin_amdgcn_mfma_f32_16x16x32_bf16(a[mi][1], b1, acc[mi][n], 0, 0, 0);
        }
    }
#pragma unroll
    for (int mi = 0; mi < 2; ++mi)
#pragma unroll
        for (int n = 0; n < 8; ++n)
#pragma unroll
            for (int r = 0; r < 4; ++r) {
                int qq = q0 + ((w * 2 + mi) << 4) + (lg << 2) + r;
                int kc = k0 + (n << 4) + lr;
                qk[((size_t)(b * S_ + qq) << 10) + kc] = acc[mi][n][r] * SCL;
            }
}

// in-register 4x4 transpose (lanes l, l^16, l^32, l^48) then b64 LDS store: T[d][kb..kb+3]
__device__ __forceinline__ void tpose_store(unsigned short (*Tls)[72], float4 p,
                                            int kb, int t) {
    const int l = t & 63, lr = l & 15, lg = l >> 4;
    float v0 = p.x, v1 = p.y, v2 = p.z, v3 = p.w;
    float y0 = __shfl_xor(v0, 16), y1 = __shfl_xor(v1, 16),
          y2 = __shfl_xor(v2, 16), y3 = __shfl_xor(v3, 16);
    bool o = (lg & 1);
    float n0 = o ? y1 : v0, n1 = o ? v1 : y0, n2 = o ? y3 : v2, n3 = o ? v3 : y2;
    float z0 = __shfl_xor(n0, 32), z1 = __shfl_xor(n1, 32),
          z2 = __shfl_xor(n2, 32), z3 = __shfl_xor(n3, 32);
    bool h = (lg & 2);
    float T0 = h ? z2 : n0, T1 = h ? z3 : n1, T2 = h ? n2 : z0, T3 = h ? n3 : z1;
    int d = (lr << 2) + lg;
    *reinterpret_cast<uint2*>(&Tls[d][kb]) = make_uint2(pack2(T0, T1), pack2(T2, T3));
}

// ---------------- K2: one block per q, all 64 batches, 512 threads
__global__ __launch_bounds__(512) void k2_mid(const float* __restrict__ Q,
                                              const float* __restrict__ AK,
                                              const float* __restrict__ AV,
                                              float* __restrict__ attn,
                                              float* __restrict__ outp) {
    __shared__ __align__(16) unsigned short Sc[64 * 1024];   // 128 KB
    __shared__ __align__(16) unsigned short Qs[64][72];
    __shared__ __align__(16) unsigned short Ak[64][72];
    __shared__ float invs[64];
    const float SCL = 0.18033688011112042f;  // log2(e)/8
    const int q = blockIdx.x;
    const int t = threadIdx.x;
    const int l = t & 63, w = t >> 6, lr = l & 15, lg = l >> 4;
    const int wq = w & 3;   // k/d quarter
    const int wh = w >> 2;  // batch half
    const int srow = t >> 3, sc8 = (t & 7) << 3;  // 64-row x 8-col staging map

    {   // Qs (pre-scaled by SCL): row srow, 8 f32
        const float* qp = &Q[((size_t)(srow * S_ + q) << 6) + sc8];
        float4 a = *reinterpret_cast<const float4*>(qp);
        float4 b = *reinterpret_cast<const float4*>(qp + 4);
        *reinterpret_cast<uint4*>(&Qs[srow][sc8]) =
            make_uint4(pack2(a.x * SCL, a.y * SCL), pack2(a.z * SCL, a.w * SCL),
                       pack2(b.x * SCL, b.y * SCL), pack2(b.z * SCL, b.w * SCL));
    }
    const float* akbase = &AK[(size_t)q << 16];
    float4 pa0, pa1;
    {   // prefetch AK tile 0
        const float* p_ = akbase + (srow << 6) + sc8;
        pa0 = *reinterpret_cast<const float4*>(p_);
        pa1 = *reinterpret_cast<const float4*>(p_ + 4);
    }
    __syncthreads();
    short8 qa[2][2];
#pragma unroll
    for (int bh = 0; bh < 2; ++bh)
#pragma unroll
        for (int h = 0; h < 2; ++h)
            qa[bh][h] = *reinterpret_cast<const short8*>(
                &Qs[(wh << 5) + (bh << 4) + lr][(h << 5) + (lg << 3)]);

    // ---- phase A: Sc[batch][k] = AKtile . (Q*SCL)^T  (C=0, b64 writes)
    for (int tt = 0; tt < 16; ++tt) {
        __syncthreads();
        *reinterpret_cast<uint4*>(&Ak[srow][sc8]) =
            make_uint4(pack2(pa0.x, pa0.y), pack2(pa0.z, pa0.w),
                       pack2(pa1.x, pa1.y), pack2(pa1.z, pa1.w));
        __syncthreads();
        if (tt < 15) {
            const float* p_ = akbase + ((size_t)(tt + 1) << 12) + (srow << 6) + sc8;
            pa0 = *reinterpret_cast<const float4*>(p_);
            pa1 = *reinterpret_cast<const float4*>(p_ + 4);
        }
        short8 ak0 = *reinterpret_cast<const short8*>(&Ak[(wq << 4) + lr][lg << 3]);
        short8 ak1 = *reinterpret_cast<const short8*>(&Ak[(wq << 4) + lr][32 + (lg << 3)]);
        int kbase = (tt << 6) + (wq << 4) + (lg << 2);
#pragma unroll
        for (int bh = 0; bh < 2; ++bh) {
            f32x4 c = {};
            c = __builtin_amdgcn_mfma_f32_16x16x32_bf16(ak0, qa[bh][0], c, 0, 0, 0);
            c = __builtin_amdgcn_mfma_f32_16x16x32_bf16(ak1, qa[bh][1], c, 0, 0, 0);
            *reinterpret_cast<uint2*>(&Sc[scidx((wh << 5) + (bh << 4) + lr, kbase)]) =
                make_uint2(pack2(c[0], c[1]), pack2(c[2], c[3]));
        }
    }
    __syncthreads();

    // prefetch AV tile 0 (in flight through combine)
    const float* avbase = &AV[(size_t)q << 16];
    float4 pv[2];
#pragma unroll
    for (int i = 0; i < 2; ++i) {
        int f = (i << 9) + t;
        pv[i] = *reinterpret_cast<const float4*>(
            &avbase[((size_t)(f >> 4) << 6) + ((f & 15) << 2)]);
    }

    // ---- combine + rowsum: P = exp2(qk_scaled + rel); s = sum (row srow, ch)
    {
        const int ch = t & 7;
        const float* qkrow = &attn[((size_t)(srow * S_ + q) << 10)];
        float s = 0.f;
#pragma unroll 4
        for (int i = 0; i < 16; ++i) {
            int k = (((i << 3) + ch) << 3);
            float4 g0 = *reinterpret_cast<const float4*>(&qkrow[k]);
            float4 g1 = *reinterpret_cast<const float4*>(&qkrow[k + 4]);
            int idx = scidx(srow, k);
            ushort8 rel = *reinterpret_cast<const ushort8*>(&Sc[idx]);
            float p0 = exp2f(g0.x + bf2f(rel[0]));
            float p1 = exp2f(g0.y + bf2f(rel[1]));
            float p2 = exp2f(g0.z + bf2f(rel[2]));
            float p3 = exp2f(g0.w + bf2f(rel[3]));
            float p4 = exp2f(g1.x + bf2f(rel[4]));
            float p5 = exp2f(g1.y + bf2f(rel[5]));
            float p6 = exp2f(g1.z + bf2f(rel[6]));
            float p7 = exp2f(g1.w + bf2f(rel[7]));
            s += ((p0 + p1) + (p2 + p3)) + ((p4 + p5) + (p6 + p7));
            ushort8 e;
            e[0] = f2bf(p0); e[1] = f2bf(p1); e[2] = f2bf(p2); e[3] = f2bf(p3);
            e[4] = f2bf(p4); e[5] = f2bf(p5); e[6] = f2bf(p6); e[7] = f2bf(p7);
            *reinterpret_cast<ushort8*>(&Sc[idx]) = e;
        }
        s += __shfl_xor(s, 1); s += __shfl_xor(s, 2); s += __shfl_xor(s, 4);
        if (ch == 0) invs[srow] = 1.0f / s;
    }
    __syncthreads();

    // ---- phase B (+ attn writes folded in): out_rel = (P . a_value[q]) * inv
    f32x4 oacc[2] = {};
    for (int tt = 0; tt < 16; ++tt) {
        __syncthreads();
        tpose_store(Ak, pv[0], (w << 2), t);
        tpose_store(Ak, pv[1], 32 + (w << 2), t);
        __syncthreads();
        if (tt < 15) {
#pragma unroll
            for (int i = 0; i < 2; ++i) {
                int f = (i << 9) + t;
                pv[i] = *reinterpret_cast<const float4*>(
                    &avbase[((size_t)(tt + 1) << 12) + ((size_t)(f >> 4) << 6) + ((f & 15) << 2)]);
            }
        }
        // attn write: rows 4tt..4tt+3, fully coalesced (wave covers 1KB runs)
        {
            int col = (t & 255) << 2;
#pragma unroll
            for (int rr = 0; rr < 2; ++rr) {
                int row = (tt << 2) + (rr << 1) + wh;
                uint2 u = *reinterpret_cast<const uint2*>(&Sc[scidx(row, col)]);
                float inv = invs[row];
                float4 o = make_float4(bf2f((unsigned short)(u.x & 0xffff)) * inv,
                                       bf2f((unsigned short)(u.x >> 16)) * inv,
                                       bf2f((unsigned short)(u.y & 0xffff)) * inv,
                                       bf2f((unsigned short)(u.y >> 16)) * inv);
                *reinterpret_cast<float4*>(&attn[((size_t)(row * S_ + q) << 10) + col]) = o;
            }
        }
        short8 bb0 = *reinterpret_cast<const short8*>(&Ak[(wq << 4) + lr][lg << 3]);
        short8 bb1 = *reinterpret_cast<const short8*>(&Ak[(wq << 4) + lr][32 + (lg << 3)]);
#pragma unroll
        for (int mi = 0; mi < 2; ++mi) {
            short8 ea0 = *reinterpret_cast<const short8*>(
                &Sc[scidx((wh << 5) + (mi << 4) + lr, (tt << 6) + (lg << 3))]);
            short8 ea1 = *reinterpret_cast<const short8*>(
                &Sc[scidx((wh << 5) + (mi << 4) + lr, (tt << 6) + 32 + (lg << 3))]);
            oacc[mi] = __builtin_amdgcn_mfma_f32_16x16x32_bf16(ea0, bb0, oacc[mi], 0, 0, 0);
            oacc[mi] = __builtin_amdgcn_mfma_f32_16x16x32_bf16(ea1, bb1, oacc[mi], 0, 0, 0);
        }
    }
#pragma unroll
    for (int mi = 0; mi < 2; ++mi)
#pragma unroll
        for (int r = 0; r < 4; ++r) {
            int brow = (wh << 5) + (mi << 4) + (lg << 2) + r;
            outp[((size_t)(brow * S_ + q) << 6) + (wq << 4) + lr] = oacc[mi][r] * invs[brow];
        }
}

// ---------------- K3: out += attn[b] . V[b]
__global__ __launch_bounds__(256) void k3_pv(const float* __restrict__ V,
                                             const float* __restrict__ attn,
                                             float* __restrict__ outp) {
    __shared__ __align__(16) unsigned short At[64][72];
    __shared__ __align__(16) unsigned short Vt[64][72];
    const int b  = blockIdx.x >> 4;
    const int q0 = (blockIdx.x & 15) << 6;
    const int t  = threadIdx.x;
    const int l = t & 63, w = t >> 6, lr = l & 15, lg = l >> 4;
    float4 pa[4], pv[4];
#pragma unroll
    for (int i = 0; i < 4; ++i) {
        int f = (i << 8) + t;
        int row = f >> 4, c = (f & 15) << 2;
        pa[i] = *reinterpret_cast<const float4*>(&attn[((size_t)(b * S_ + q0 + row) << 10) + c]);
        pv[i] = *reinterpret_cast<const float4*>(&V[((size_t)(b * S_ + row) << 6) + c]);
    }
    f32x4 acc[4] = {};
    for (int tt = 0; tt < 16; ++tt) {
        __syncthreads();
#pragma unroll
        for (int i = 0; i < 4; ++i) {
            int f = (i << 8) + t;
            int row = f >> 4, c = (f & 15) << 2;
            *reinterpret_cast<uint2*>(&At[row][c]) =
                make_uint2(pack2(pa[i].x, pa[i].y), pack2(pa[i].z, pa[i].w));
            tpose_store(Vt, pv[i], (i << 4) + (w << 2), t);
        }
        __syncthreads();
        if (tt < 15) {
#pragma unroll
            for (int i = 0; i < 4; ++i) {
                int f = (i << 8) + t;
                int row = f >> 4, c = (f & 15) << 2;
                pa[i] = *reinterpret_cast<const float4*>(
                    &attn[((size_t)(b * S_ + q0 + row) << 10) + ((tt + 1) << 6) + c]);
                pv[i] = *reinterpret_cast<const float4*>(
                    &V[((size_t)(b * S_ + ((tt + 1) << 6) + row) << 6) + c]);
            }
        }
        short8 a0 = *reinterpret_cast<const short8*>(&At[(w << 4) + lr][lg * 8]);
        short8 a1 = *reinterpret_cast<const short8*>(&At[(w << 4) + lr][32 + lg * 8]);
#pragma unroll
        for (int n = 0; n < 4; ++n) {
            short8 b0 = *reinterpret_cast<const short8*>(&Vt[(n << 4) + lr][lg * 8]);
            short8 b1 = *reinterpret_cast<const short8*>(&Vt[(n << 4) + lr][32 + lg * 8]);
            acc[n] = __builtin_amdgcn_mfma_f32_16x16x32_bf16(a0, b0, acc[n], 0, 0, 0);
            acc[n] = __builtin_amdgcn_mfma_f32_16x16x32_bf16(a1, b1, acc[n], 0, 0, 0);
        }
    }
#pragma unroll
    for (int n = 0; n < 4; ++n)
#pragma unroll
        for (int r = 0; r < 4; ++r) {
            size_t idx = ((size_t)(b * S_ + q0 + (w << 4) + (lg << 2) + r) << 6) + (n << 4) + lr;
            outp[idx] += acc[n][r];
        }
}

extern "C" void kernel_launch(void* const* d_in, const int* in_sizes, int n_in,
                              void* d_out, int out_size, void* d_ws, size_t ws_size,
                              hipStream_t stream) {
    (void)in_sizes; (void)n_in; (void)out_size; (void)d_ws; (void)ws_size;
    const float* Q  = (const float*)d_in[0];
    const float* K  = (const float*)d_in[1];
    const float* V  = (const float*)d_in[2];
    const float* AK = (const float*)d_in[3];
    const float* AV = (const float*)d_in[4];
    float* outp = (float*)d_out;
    float* attn = outp + (size_t)B_ * S_ * D_;

    k1_qk <<<dim3(64 * 8 * 8), dim3(256), 0, stream>>>(Q, K, attn);
    k2_mid<<<dim3(1024),       dim3(512), 0, stream>>>(Q, AK, AV, attn, outp);
    k3_pv <<<dim3(64 * 16),    dim3(256), 0, stream>>>(V, attn, outp);
}

// Round 8
// 405.637 us; speedup vs baseline: 1.6518x; 1.0039x over previous
//
#include <hip/hip_runtime.h>
#include <stdint.h>

#define S_ 1024
#define D_ 64
#define B_ 64

typedef short short8 __attribute__((ext_vector_type(8)));
typedef unsigned short ushort8 __attribute__((ext_vector_type(8)));
typedef float f32x4 __attribute__((ext_vector_type(4)));

__device__ __forceinline__ unsigned short f2bf(float x) {
    uint32_t u = __builtin_bit_cast(uint32_t, x);
    return (unsigned short)((u + 0x7FFFu + ((u >> 16) & 1u)) >> 16);
}
__device__ __forceinline__ float bf2f(unsigned short b) {
    return __builtin_bit_cast(float, ((uint32_t)b) << 16);
}
__device__ __forceinline__ uint32_t pack2(float a, float b) {
    return (uint32_t)f2bf(a) | ((uint32_t)f2bf(b) << 16);
}
// XOR-swizzled index into the row x 1024 bf16 score buffer (16B-chunk swizzle by row&15)
__device__ __forceinline__ int scidx(int row, int k) {
    return (((row << 10) + (k & ~7)) ^ ((row & 15) << 3)) + (k & 7);
}

// ---------------- K1: qk[b,q,k] = (Q[b,q,:].K[b,k,:]) * SCL  (f32 into attn region)
__global__ __launch_bounds__(256) void k1_qk(const float* __restrict__ Q,
                                             const float* __restrict__ Kk,
                                             float* __restrict__ qk) {
    __shared__ __align__(16) unsigned short Qs[128][72];
    __shared__ __align__(16) unsigned short Ks[128][72];
    const float SCL = 0.18033688011112042f;  // log2(e)/8
    const int bx = blockIdx.x;
    const int b  = bx >> 6;
    const int q0 = ((bx >> 3) & 7) << 7;
    const int k0 = (bx & 7) << 7;
    const int t  = threadIdx.x;
#pragma unroll
    for (int i = 0; i < 8; ++i) {
        int f = (i << 8) + t;
        int row = f >> 4, c = (f & 15) << 2;
        float4 v = *reinterpret_cast<const float4*>(&Q[((size_t)(b * S_ + q0 + row) << 6) + c]);
        *reinterpret_cast<uint2*>(&Qs[row][c]) = make_uint2(pack2(v.x, v.y), pack2(v.z, v.w));
        float4 u = *reinterpret_cast<const float4*>(&Kk[((size_t)(b * S_ + k0 + row) << 6) + c]);
        *reinterpret_cast<uint2*>(&Ks[row][c]) = make_uint2(pack2(u.x, u.y), pack2(u.z, u.w));
    }
    __syncthreads();
    const int l = t & 63, w = t >> 6, lr = l & 15, lg = l >> 4;
    short8 a[2][2];
#pragma unroll
    for (int mi = 0; mi < 2; ++mi)
#pragma unroll
        for (int h = 0; h < 2; ++h)
            a[mi][h] = *reinterpret_cast<const short8*>(&Qs[((w * 2 + mi) << 4) + lr][h * 32 + lg * 8]);
    f32x4 acc[2][8] = {};
#pragma unroll
    for (int n = 0; n < 8; ++n) {
        short8 b0 = *reinterpret_cast<const short8*>(&Ks[(n << 4) + lr][lg * 8]);
        short8 b1 = *reinterpret_cast<const short8*>(&Ks[(n << 4) + lr][32 + lg * 8]);
#pragma unroll
        for (int mi = 0; mi < 2; ++mi) {
            acc[mi][n] = __builtin_amdgcn_mfma_f32_16x16x32_bf16(a[mi][0], b0, acc[mi][n], 0, 0, 0);
            acc[mi][n] = __builtin_amdgcn_mfma_f32_16x16x32_bf16(a[mi][1], b1, acc[mi][n], 0, 0, 0);
        }
    }
#pragma unroll
    for (int mi = 0; mi < 2; ++mi)
#pragma unroll
        for (int n = 0; n < 8; ++n)
#pragma unroll
            for (int r = 0; r < 4; ++r) {
                int qq = q0 + ((w * 2 + mi) << 4) + (lg << 2) + r;
                int kc = k0 + (n << 4) + lr;
                qk[((size_t)(b * S_ + qq) << 10) + kc] = acc[mi][n][r] * SCL;
            }
}

// in-register 4x4 transpose (lanes l, l^16, l^32, l^48) then b64 store: T[d][kb..kb+3]
__device__ __forceinline__ void tpose_store_p(unsigned short* Tls, int pitch, float4 p,
                                              int kb, int t) {
    const int l = t & 63, lr = l & 15, lg = l >> 4;
    float v0 = p.x, v1 = p.y, v2 = p.z, v3 = p.w;
    float y0 = __shfl_xor(v0, 16), y1 = __shfl_xor(v1, 16),
          y2 = __shfl_xor(v2, 16), y3 = __shfl_xor(v3, 16);
    bool o = (lg & 1);
    float n0 = o ? y1 : v0, n1 = o ? v1 : y0, n2 = o ? y3 : v2, n3 = o ? v3 : y2;
    float z0 = __shfl_xor(n0, 32), z1 = __shfl_xor(n1, 32),
          z2 = __shfl_xor(n2, 32), z3 = __shfl_xor(n3, 32);
    bool h = (lg & 2);
    float T0 = h ? z2 : n0, T1 = h ? z3 : n1, T2 = h ? n2 : z0, T3 = h ? n3 : z1;
    int d = (lr << 2) + lg;
    *reinterpret_cast<uint2*>(&Tls[d * pitch + kb]) = make_uint2(pack2(T0, T1), pack2(T2, T3));
}

// ---------------- K2: one block per q, all 64 batches, 512 threads
__global__ __launch_bounds__(512) void k2_mid(const float* __restrict__ Q,
                                              const float* __restrict__ AK,
                                              const float* __restrict__ AV,
                                              float* __restrict__ attn,
                                              float* __restrict__ outp) {
    __shared__ __align__(16) unsigned short Sc[64 * 1024];     // 128 KB
    __shared__ __align__(16) unsigned short Qs[64][72];
    __shared__ __align__(16) unsigned short Ak[2][64][72];     // double-buffered
    __shared__ float invs[64];
    const float SCL = 0.18033688011112042f;  // log2(e)/8
    const int q = blockIdx.x;
    const int t = threadIdx.x;
    const int l = t & 63, w = t >> 6, lr = l & 15, lg = l >> 4;
    const int wq = w & 3;   // k/d quarter
    const int wh = w >> 2;  // batch half
    const int srow = t >> 3, sc8 = (t & 7) << 3;  // 64-row x 8-col staging map

    {   // Qs (pre-scaled by SCL): row srow, 8 f32
        const float* qp = &Q[((size_t)(srow * S_ + q) << 6) + sc8];
        float4 a = *reinterpret_cast<const float4*>(qp);
        float4 b = *reinterpret_cast<const float4*>(qp + 4);
        *reinterpret_cast<uint4*>(&Qs[srow][sc8]) =
            make_uint4(pack2(a.x * SCL, a.y * SCL), pack2(a.z * SCL, a.w * SCL),
                       pack2(b.x * SCL, b.y * SCL), pack2(b.z * SCL, b.w * SCL));
    }
    const float* akbase = &AK[(size_t)q << 16];
    float4 pa[2][2];
#define LDK(set, tile) do { const float* p_ = akbase + ((size_t)(tile) << 12) + (srow << 6) + sc8; \
        pa[set][0] = *reinterpret_cast<const float4*>(p_);                                         \
        pa[set][1] = *reinterpret_cast<const float4*>(p_ + 4); } while (0)
#define STAGEK(buf) do {                                                                     \
        *reinterpret_cast<uint4*>(&Ak[buf][srow][sc8]) =                                     \
            make_uint4(pack2(pa[buf][0].x, pa[buf][0].y), pack2(pa[buf][0].z, pa[buf][0].w), \
                       pack2(pa[buf][1].x, pa[buf][1].y), pack2(pa[buf][1].z, pa[buf][1].w)); } while (0)
    LDK(0, 0); LDK(1, 1);
    __syncthreads();   // Qs ready
    short8 qa[2][2];
#pragma unroll
    for (int bh = 0; bh < 2; ++bh)
#pragma unroll
        for (int h = 0; h < 2; ++h)
            qa[bh][h] = *reinterpret_cast<const short8*>(
                &Qs[(wh << 5) + (bh << 4) + lr][(h << 5) + (lg << 3)]);
    STAGEK(0);
    __syncthreads();

    // ---- phase A: Sc[batch][k] = AKtile . (Q*SCL)^T  (1 barrier/tile, dbuf)
#pragma unroll 2
    for (int tt = 0; tt < 16; ++tt) {
        const int cur = tt & 1, nxt = cur ^ 1;
        short8 ak0 = *reinterpret_cast<const short8*>(&Ak[cur][(wq << 4) + lr][lg << 3]);
        short8 ak1 = *reinterpret_cast<const short8*>(&Ak[cur][(wq << 4) + lr][32 + (lg << 3)]);
        if (tt < 15) STAGEK(nxt);
        if (tt < 14) LDK(cur, tt + 2);
        int kbase = (tt << 6) + (wq << 4) + (lg << 2);
#pragma unroll
        for (int bh = 0; bh < 2; ++bh) {
            f32x4 c = {};
            c = __builtin_amdgcn_mfma_f32_16x16x32_bf16(ak0, qa[bh][0], c, 0, 0, 0);
            c = __builtin_amdgcn_mfma_f32_16x16x32_bf16(ak1, qa[bh][1], c, 0, 0, 0);
            *reinterpret_cast<uint2*>(&Sc[scidx((wh << 5) + (bh << 4) + lr, kbase)]) =
                make_uint2(pack2(c[0], c[1]), pack2(c[2], c[3]));
        }
        __syncthreads();
    }
#undef LDK
#undef STAGEK

    // prefetch AV tiles 0,1 (in flight through combine)
    const float* avbase = &AV[(size_t)q << 16];
    float4 pv[2][2];
#pragma unroll
    for (int s = 0; s < 2; ++s)
#pragma unroll
        for (int i = 0; i < 2; ++i) {
            int f = (i << 9) + t;
            pv[s][i] = *reinterpret_cast<const float4*>(
                &avbase[((size_t)s << 12) + ((size_t)(f >> 4) << 6) + ((f & 15) << 2)]);
        }

    // ---- combine + rowsum: P = exp2(qk_scaled + rel); s = sum (row srow, ch)
    {
        const int ch = t & 7;
        const float* qkrow = &attn[((size_t)(srow * S_ + q) << 10)];
        float s = 0.f;
#pragma unroll 4
        for (int i = 0; i < 16; ++i) {
            int k = (((i << 3) + ch) << 3);
            float4 g0 = *reinterpret_cast<const float4*>(&qkrow[k]);
            float4 g1 = *reinterpret_cast<const float4*>(&qkrow[k + 4]);
            int idx = scidx(srow, k);
            ushort8 rel = *reinterpret_cast<const ushort8*>(&Sc[idx]);
            float p0 = exp2f(g0.x + bf2f(rel[0]));
            float p1 = exp2f(g0.y + bf2f(rel[1]));
            float p2 = exp2f(g0.z + bf2f(rel[2]));
            float p3 = exp2f(g0.w + bf2f(rel[3]));
            float p4 = exp2f(g1.x + bf2f(rel[4]));
            float p5 = exp2f(g1.y + bf2f(rel[5]));
            float p6 = exp2f(g1.z + bf2f(rel[6]));
            float p7 = exp2f(g1.w + bf2f(rel[7]));
            s += ((p0 + p1) + (p2 + p3)) + ((p4 + p5) + (p6 + p7));
            ushort8 e;
            e[0] = f2bf(p0); e[1] = f2bf(p1); e[2] = f2bf(p2); e[3] = f2bf(p3);
            e[4] = f2bf(p4); e[5] = f2bf(p5); e[6] = f2bf(p6); e[7] = f2bf(p7);
            *reinterpret_cast<ushort8*>(&Sc[idx]) = e;
        }
        s += __shfl_xor(s, 1); s += __shfl_xor(s, 2); s += __shfl_xor(s, 4);
        if (ch == 0) invs[srow] = 1.0f / s;
    }
    __syncthreads();

    // ---- phase B prologue: stage AV tile 0 into Ak[0]
    tpose_store_p(&Ak[0][0][0], 72, pv[0][0], (w << 2), t);
    tpose_store_p(&Ak[0][0][0], 72, pv[0][1], 32 + (w << 2), t);
    __syncthreads();

    // ---- phase B (+ attn writes folded in): out_rel = (P . a_value[q]) * inv
    f32x4 oacc[2] = {};
#pragma unroll 2
    for (int tt = 0; tt < 16; ++tt) {
        const int cur = tt & 1, nxt = cur ^ 1;
        short8 bb0 = *reinterpret_cast<const short8*>(&Ak[cur][(wq << 4) + lr][lg << 3]);
        short8 bb1 = *reinterpret_cast<const short8*>(&Ak[cur][(wq << 4) + lr][32 + (lg << 3)]);
        if (tt < 15) {
            tpose_store_p(&Ak[nxt][0][0], 72, pv[nxt][0], (w << 2), t);
            tpose_store_p(&Ak[nxt][0][0], 72, pv[nxt][1], 32 + (w << 2), t);
        }
        if (tt < 14) {
#pragma unroll
            for (int i = 0; i < 2; ++i) {
                int f = (i << 9) + t;
                pv[cur][i] = *reinterpret_cast<const float4*>(
                    &avbase[((size_t)(tt + 2) << 12) + ((size_t)(f >> 4) << 6) + ((f & 15) << 2)]);
            }
        }
        // attn write: rows 4tt..4tt+3, fully coalesced (wave covers 1KB runs)
        {
            int col = (t & 255) << 2;
#pragma unroll
            for (int rr = 0; rr < 2; ++rr) {
                int row = (tt << 2) + (rr << 1) + wh;
                uint2 u = *reinterpret_cast<const uint2*>(&Sc[scidx(row, col)]);
                float inv = invs[row];
                float4 o = make_float4(bf2f((unsigned short)(u.x & 0xffff)) * inv,
                                       bf2f((unsigned short)(u.x >> 16)) * inv,
                                       bf2f((unsigned short)(u.y & 0xffff)) * inv,
                                       bf2f((unsigned short)(u.y >> 16)) * inv);
                *reinterpret_cast<float4*>(&attn[((size_t)(row * S_ + q) << 10) + col]) = o;
            }
        }
#pragma unroll
        for (int mi = 0; mi < 2; ++mi) {
            short8 ea0 = *reinterpret_cast<const short8*>(
                &Sc[scidx((wh << 5) + (mi << 4) + lr, (tt << 6) + (lg << 3))]);
            short8 ea1 = *reinterpret_cast<const short8*>(
                &Sc[scidx((wh << 5) + (mi << 4) + lr, (tt << 6) + 32 + (lg << 3))]);
            oacc[mi] = __builtin_amdgcn_mfma_f32_16x16x32_bf16(ea0, bb0, oacc[mi], 0, 0, 0);
            oacc[mi] = __builtin_amdgcn_mfma_f32_16x16x32_bf16(ea1, bb1, oacc[mi], 0, 0, 0);
        }
        __syncthreads();
    }
#pragma unroll
    for (int mi = 0; mi < 2; ++mi)
#pragma unroll
        for (int r = 0; r < 4; ++r) {
            int brow = (wh << 5) + (mi << 4) + (lg << 2) + r;
            outp[((size_t)(brow * S_ + q) << 6) + (wq << 4) + lr] = oacc[mi][r] * invs[brow];
        }
}

// ---------------- K3: out += attn[b] . V[b]   (V^T resident in LDS, 256 blocks x 512)
__global__ __launch_bounds__(512) void k3_pv(const float* __restrict__ V,
                                             const float* __restrict__ attn,
                                             float* __restrict__ outp) {
    __shared__ __align__(16) unsigned short Vt[64 * 1032];   // V^T bf16, pitch 1032
    __shared__ __align__(16) unsigned short At[2][64][72];
    const int b  = blockIdx.x >> 2;
    const int qq = blockIdx.x & 3;
    const int t  = threadIdx.x;
    const int l = t & 63, w = t >> 6, lr = l & 15, lg = l >> 4;
    const int wq = w & 3;   // q 16-block within 64-row subtile
    const int dh = w >> 2;  // d half
    const int srow = t >> 3, sc8 = (t & 7) << 3;

    // stage V^T once: 16 k-tiles, transpose via shuffles
    for (int kt = 0; kt < 16; ++kt) {
#pragma unroll
        for (int i = 0; i < 2; ++i) {
            int f = (i << 9) + t;
            int row = f >> 4, c = (f & 15) << 2;
            float4 pvv = *reinterpret_cast<const float4*>(
                &V[((size_t)(b * S_ + (kt << 6) + row) << 6) + c]);
            tpose_store_p(&Vt[0], 1032, pvv, (kt << 6) + (i << 5) + (w << 2), t);
        }
    }
    __syncthreads();

    for (int qs = 0; qs < 4; ++qs) {
        const float* arow = &attn[((size_t)((b * S_ + (qq << 8) + (qs << 6) + srow)) << 10) + sc8];
        float4 pa[2][2];
#define LDA3(set, tile) do { const float* p_ = arow + ((tile) << 6);       \
        pa[set][0] = *reinterpret_cast<const float4*>(p_);                 \
        pa[set][1] = *reinterpret_cast<const float4*>(p_ + 4); } while (0)
#define STAGEA(buf) do {                                                                     \
        *reinterpret_cast<uint4*>(&At[buf][srow][sc8]) =                                     \
            make_uint4(pack2(pa[buf][0].x, pa[buf][0].y), pack2(pa[buf][0].z, pa[buf][0].w), \
                       pack2(pa[buf][1].x, pa[buf][1].y), pack2(pa[buf][1].z, pa[buf][1].w)); } while (0)
        LDA3(0, 0); LDA3(1, 1);
        __syncthreads();   // previous subtile's At reads done
        STAGEA(0);
        __syncthreads();
        f32x4 acc[2] = {};
#pragma unroll 2
        for (int kt = 0; kt < 16; ++kt) {
            const int cur = kt & 1, nxt = cur ^ 1;
            short8 a0 = *reinterpret_cast<const short8*>(&At[cur][(wq << 4) + lr][lg << 3]);
            short8 a1 = *reinterpret_cast<const short8*>(&At[cur][(wq << 4) + lr][32 + (lg << 3)]);
            if (kt < 15) STAGEA(nxt);
            if (kt < 14) LDA3(cur, kt + 2);
#pragma unroll
            for (int n = 0; n < 2; ++n) {
                const unsigned short* vb = &Vt[((dh << 5) + (n << 4) + lr) * 1032 + (kt << 6) + (lg << 3)];
                short8 b0 = *reinterpret_cast<const short8*>(vb);
                short8 b1 = *reinterpret_cast<const short8*>(vb + 32);
                acc[n] = __builtin_amdgcn_mfma_f32_16x16x32_bf16(a0, b0, acc[n], 0, 0, 0);
                acc[n] = __builtin_amdgcn_mfma_f32_16x16x32_bf16(a1, b1, acc[n], 0, 0, 0);
            }
            __syncthreads();
        }
#undef LDA3
#undef STAGEA
#pragma unroll
        for (int n = 0; n < 2; ++n)
#pragma unroll
            for (int r = 0; r < 4; ++r) {
                size_t idx = ((size_t)(b * S_ + (qq << 8) + (qs << 6) + (wq << 4) + (lg << 2) + r) << 6)
                             + (dh << 5) + (n << 4) + lr;
                outp[idx] += acc[n][r];
            }
    }
}

extern "C" void kernel_launch(void* const* d_in, const int* in_sizes, int n_in,
                              void* d_out, int out_size, void* d_ws, size_t ws_size,
                              hipStream_t stream) {
    (void)in_sizes; (void)n_in; (void)out_size; (void)d_ws; (void)ws_size;
    const float* Q  = (const float*)d_in[0];
    const float* K  = (const float*)d_in[1];
    const float* V  = (const float*)d_in[2];
    const float* AK = (const float*)d_in[3];
    const float* AV = (const float*)d_in[4];
    float* outp = (float*)d_out;
    float* attn = outp + (size_t)B_ * S_ * D_;

    k1_qk <<<dim3(64 * 8 * 8), dim3(256), 0, stream>>>(Q, K, attn);
    k2_mid<<<dim3(1024),       dim3(512), 0, stream>>>(Q, AK, AV, attn, outp);
    k3_pv <<<dim3(256),        dim3(512), 0, stream>>>(V, attn, outp);
}